// Round 6
// baseline (337.186 us; speedup 1.0000x reference)
//
#include <hip/hip_runtime.h>
#include <cstdint>
#include <cstddef>

// ---------------- problem constants ----------------
#define SCALEQ 0.17677669529663689f // 32^-0.5

typedef _Float16 half_t;
typedef _Float16 half8   __attribute__((ext_vector_type(8)));
typedef _Float16 half4v  __attribute__((ext_vector_type(4)));
typedef float    float4v __attribute__((ext_vector_type(4)));

#define GLDS16(gp, lp)                                                        \
  __builtin_amdgcn_global_load_lds(                                           \
      (const __attribute__((address_space(1))) void*)(gp),                    \
      (__attribute__((address_space(3))) void*)(lp), 16, 0, 0)

// ---------------- merged prep kernel (r5-verified) ----------------
__global__ __launch_bounds__(256) void prep_all(
    const float* __restrict__ x, const float* __restrict__ dwconv_w,
    const float* __restrict__ qkv_w, const float* __restrict__ proj_w,
    const float* __restrict__ rpb, half_t* __restrict__ xpad,
    half_t* __restrict__ Wt, half_t* __restrict__ qw16,
    half_t* __restrict__ pw16, float* __restrict__ btab) {
  __shared__ float tile[128 * 65];
  const int blk = blockIdx.x, t = threadIdx.x;
  if (blk < 800) {
    const int bd = blk, b = bd / 100, d = bd % 100;
    for (int hf = 0; hf < 2; ++hf) {
      for (int i = 0; i < 32; ++i) {
        int idx = i * 256 + t, c = idx >> 6, hw = idx & 63;
        tile[c * 65 + hw] = x[(size_t)((b * 256 + hf * 128 + c) * 100 + d) * 64 + hw];
      }
      __syncthreads();
      for (int i = 0; i < 50; ++i) {
        int idx = i * 256 + t, cell = idx >> 7, c = idx & 127;
        int hh = cell / 10, ww = cell % 10;
        float v = 0.f;
        if (hh >= 1 && hh <= 8 && ww >= 1 && ww <= 8)
          v = tile[c * 65 + (hh - 1) * 8 + (ww - 1)];
        xpad[(size_t)(bd * 100 + cell) * 256 + hf * 128 + c] = (half_t)v;
      }
      __syncthreads();
    }
  } else if (blk < 944) {        // convw: Wt[tap][o][c]
    const int base = (blk - 800) * 4096;
#pragma unroll
    for (int i = 0; i < 16; ++i) {
      int idx = base + i * 256 + t;
      int tap = idx >> 16, rem = idx & 65535;
      int o = rem >> 8, c = rem & 255;
      Wt[idx] = (half_t)dwconv_w[(o * 256 + c) * 9 + tap];
    }
  } else if (blk < 1040) {       // qkvw (q rows pre-scaled)
    const int base = (blk - 944) * 2048;
#pragma unroll
    for (int i = 0; i < 8; ++i) {
      int idx = base + i * 256 + t;
      float v = qkv_w[idx];
      if (idx < 65536) v *= SCALEQ;
      qw16[idx] = (half_t)v;
    }
  } else if (blk < 1072) {       // projw
    const int base = (blk - 1040) * 2048;
#pragma unroll
    for (int i = 0; i < 8; ++i) {
      int idx = base + i * 256 + t;
      pw16[idx] = (half_t)proj_w[idx];
    }
  } else {                       // bias table btab[head][n][m]
    const int base = (blk - 1072) * 2048;
#pragma unroll
    for (int i = 0; i < 8; ++i) {
      int idx = base + i * 256 + t;
      int hd = idx >> 12, n = (idx >> 6) & 63, m = idx & 63;
      int h1 = n >> 3, w1 = n & 7, h2 = m >> 3, w2 = m & 7;
      int ridx = (h1 - h2 + 7) * 15 + (w1 - w2 + 7);
      btab[idx] = rpb[ridx * 8 + hd];
    }
  }
}

// ---------------- conv implicit GEMM (unchanged, verified) ----------------
__global__ __launch_bounds__(256) void conv_kernel(
    const half_t* __restrict__ Wt, const half_t* __restrict__ xpad,
    const float* __restrict__ convb, half_t* __restrict__ xl) {
  __shared__ __align__(16) half_t Asm[128 * 64];
  __shared__ __align__(16) half_t Bsm[128 * 64];
  const int blk = blockIdx.x;
  const int o0 = (blk & 1) * 128;
  const int n0 = (blk >> 1) * 128;
  const int tid = threadIdx.x;
  const int wave = tid >> 6, lane = tid & 63;
  const int l15 = lane & 15, quad = lane >> 4;
  const int wm = wave >> 1, wn = wave & 1;
  const int srow = tid >> 3;
  const int cg = (tid & 7) ^ (srow & 7);

  int pixbase[4], arow[4];
#pragma unroll
  for (int i = 0; i < 4; ++i) {
    int P = n0 + srow + i * 32;
    int bd = P >> 6, hw = P & 63;
    pixbase[i] = (bd * 100 + (hw >> 3) * 10 + (hw & 7)) * 512 + cg * 16;
    arow[i] = (o0 + srow + i * 32) * 512 + cg * 16;
  }

  float4v acc[4][4];
#pragma unroll
  for (int mi = 0; mi < 4; ++mi)
#pragma unroll
    for (int ni = 0; ni < 4; ++ni) {
      float4v z = {0.f, 0.f, 0.f, 0.f};
      acc[mi][ni] = z;
    }

  const char* xpc = (const char*)xpad;
  for (int tap = 0; tap < 9; ++tap) {
    const char* wt = (const char*)Wt + tap * 131072;
    const int toff = ((tap / 3) * 10 + (tap % 3)) * 512;
    for (int c0 = 0; c0 < 512; c0 += 128) {
#pragma unroll
      for (int i = 0; i < 4; ++i) {
        GLDS16(wt + arow[i] + c0, (char*)Asm + i * 4096 + wave * 1024);
        GLDS16(xpc + pixbase[i] + toff + c0, (char*)Bsm + i * 4096 + wave * 1024);
      }
      __syncthreads();
#pragma unroll
      for (int kh = 0; kh < 2; ++kh) {
        half8 af[4], bf[4];
#pragma unroll
        for (int mi = 0; mi < 4; ++mi) {
          int r = wm * 64 + mi * 16 + l15;
          af[mi] = *(const half8*)&Asm[r * 64 + (((kh * 4 + quad) ^ (r & 7)) * 8)];
        }
#pragma unroll
        for (int ni = 0; ni < 4; ++ni) {
          int r = wn * 64 + ni * 16 + l15;
          bf[ni] = *(const half8*)&Bsm[r * 64 + (((kh * 4 + quad) ^ (r & 7)) * 8)];
        }
#pragma unroll
        for (int mi = 0; mi < 4; ++mi)
#pragma unroll
          for (int ni = 0; ni < 4; ++ni)
            acc[mi][ni] = __builtin_amdgcn_mfma_f32_16x16x32_f16(
                af[mi], bf[ni], acc[mi][ni], 0, 0, 0);
      }
      __syncthreads();
    }
  }
#pragma unroll
  for (int mi = 0; mi < 4; ++mi) {
    const int o4 = o0 + wm * 64 + mi * 16 + quad * 4;
    const float b0 = convb[o4], b1 = convb[o4 + 1], b2 = convb[o4 + 2], b3 = convb[o4 + 3];
#pragma unroll
    for (int ni = 0; ni < 4; ++ni) {
      const int P = n0 + wn * 64 + ni * 16 + l15;
      half4v h;
      h.x = (half_t)(acc[mi][ni].x + b0);
      h.y = (half_t)(acc[mi][ni].y + b1);
      h.z = (half_t)(acc[mi][ni].z + b2);
      h.w = (half_t)(acc[mi][ni].w + b3);
      *(half4v*)(xl + (size_t)P * 256 + o4) = h;
    }
  }
}

// ---------------- fused qkv + attention + proj ----------------
// grid 800 (one bd slice), block 512 (8 waves = 1 wave per head).
// r6 change: q/k/v GEMMs merged into ONE kh loop (bf read once, 3 acc sets,
// 24 independent MFMA chains) -> 3x fewer xlp ds_read_b128, more ILP.
__global__ __launch_bounds__(512) void fused_tail3(
    const half_t* __restrict__ xlg, const half_t* __restrict__ qw,
    const float* __restrict__ qkvb, const float* __restrict__ btab,
    const half_t* __restrict__ pw, const float* __restrict__ projb,
    float* __restrict__ out32) {
  __shared__ __align__(16) half_t LS[78336];   // 156672 B
  const int bd = blockIdx.x;
  const int tid = threadIdx.x;
  const int wave = tid >> 6, lane = tid & 63;
  const int l15 = lane & 15, quad = lane >> 4;
  const int head = wave;

  half_t* xlp = LS;
  half_t* xa = LS;                      // [64][264] overlay after barrier
  float* T = (float*)LS;                // [64][68] fp32 overlay at the end
  half_t* scr = LS + 16896 + wave * 7680;
  half_t* qsc = scr;                    // [64][40]
  half_t* ksc = scr + 2560;             // [64][40]
  half_t* vsc = scr + 5120;             // [32][72]
  half_t* Psc = scr;                    // [64][72] (over q+k)

  // ---- stage xl[bd] (32 KB), XOR-swizzled 16B chunks ----
  {
    const char* src = (const char*)(xlg + (size_t)bd * 64 * 256);
#pragma unroll
    for (int i = 0; i < 4; ++i) {
      int row = i * 16 + wave * 2 + (lane >> 5);
      int sch = (lane & 31) ^ (row & 7);
      GLDS16(src + row * 512 + sch * 16, (char*)xlp + (i * 16 + wave * 2) * 512);
    }
  }
  __syncthreads();

  // ---- merged q/k/v GEMM: M=32 each, N=64 px, K=256, one xlp pass ----
  {
    const half_t* Wq0 = qw + head * 32 * 256;
    const half_t* Wk0 = qw + 65536 + head * 32 * 256;
    const half_t* Wv0 = qw + 131072 + head * 32 * 256;
    float4v aq[2][4], ak[2][4], av4[2][4];
#pragma unroll
    for (int mi = 0; mi < 2; ++mi)
#pragma unroll
      for (int ni = 0; ni < 4; ++ni) {
        float4v z = {0.f, 0.f, 0.f, 0.f};
        aq[mi][ni] = z; ak[mi][ni] = z; av4[mi][ni] = z;
      }
#pragma unroll
    for (int kh = 0; kh < 8; ++kh) {
      half8 bf[4];
#pragma unroll
      for (int ni = 0; ni < 4; ++ni) {
        int r = ni * 16 + l15;
        bf[ni] = *(const half8*)&xlp[r * 256 + (((kh * 4 + quad) ^ (r & 7)) * 8)];
      }
      half8 fq[2], fk[2], fv[2];
#pragma unroll
      for (int mi = 0; mi < 2; ++mi) {
        const int ro = (mi * 16 + l15) * 256 + kh * 32 + quad * 8;
        fq[mi] = *(const half8*)(Wq0 + ro);
        fk[mi] = *(const half8*)(Wk0 + ro);
        fv[mi] = *(const half8*)(Wv0 + ro);
      }
#pragma unroll
      for (int mi = 0; mi < 2; ++mi)
#pragma unroll
        for (int ni = 0; ni < 4; ++ni) {
          aq[mi][ni] = __builtin_amdgcn_mfma_f32_16x16x32_f16(fq[mi], bf[ni], aq[mi][ni], 0, 0, 0);
          ak[mi][ni] = __builtin_amdgcn_mfma_f32_16x16x32_f16(fk[mi], bf[ni], ak[mi][ni], 0, 0, 0);
          av4[mi][ni] = __builtin_amdgcn_mfma_f32_16x16x32_f16(fv[mi], bf[ni], av4[mi][ni], 0, 0, 0);
        }
    }
    // epilogues -> wave-private scratch
#pragma unroll
    for (int mi = 0; mi < 2; ++mi) {
      const float4v bq = *(const float4v*)&qkvb[head * 32 + mi * 16 + quad * 4];
      const float4v bk4 = *(const float4v*)&qkvb[256 + head * 32 + mi * 16 + quad * 4];
      const float4v bv = *(const float4v*)&qkvb[512 + head * 32 + mi * 16 + quad * 4];
#pragma unroll
      for (int ni = 0; ni < 4; ++ni) {
        half4v hq, hk;
        hq.x = (half_t)(aq[mi][ni].x + bq.x * SCALEQ);
        hq.y = (half_t)(aq[mi][ni].y + bq.y * SCALEQ);
        hq.z = (half_t)(aq[mi][ni].z + bq.z * SCALEQ);
        hq.w = (half_t)(aq[mi][ni].w + bq.w * SCALEQ);
        *(half4v*)(qsc + (ni * 16 + l15) * 40 + mi * 16 + quad * 4) = hq;
        hk.x = (half_t)(ak[mi][ni].x + bk4.x);
        hk.y = (half_t)(ak[mi][ni].y + bk4.y);
        hk.z = (half_t)(ak[mi][ni].z + bk4.z);
        hk.w = (half_t)(ak[mi][ni].w + bk4.w);
        *(half4v*)(ksc + (ni * 16 + l15) * 40 + mi * 16 + quad * 4) = hk;
#pragma unroll
        for (int iv = 0; iv < 4; ++iv)
          vsc[(mi * 16 + quad * 4 + iv) * 72 + ni * 16 + l15] =
              (half_t)(av4[mi][ni][iv] + bv[iv]);
      }
    }
  }

  __builtin_amdgcn_s_waitcnt(0);  // q/k/v scratch writes -> own reads

  // ---- QK^T + bias + softmax ----
  half8 aq[4], bk[4];
#pragma unroll
  for (int i = 0; i < 4; ++i) {
    aq[i] = *(const half8*)(qsc + (i * 16 + l15) * 40 + quad * 8);
    bk[i] = *(const half8*)(ksc + (i * 16 + l15) * 40 + quad * 8);
  }
  float4v s[4][4];
#pragma unroll
  for (int ni = 0; ni < 4; ++ni)
#pragma unroll
    for (int mi = 0; mi < 4; ++mi) {
      float4v z = {0.f, 0.f, 0.f, 0.f};
      s[ni][mi] = __builtin_amdgcn_mfma_f32_16x16x32_f16(aq[ni], bk[mi], z, 0, 0, 0);
    }
  const float* bh = btab + head * 4096;
#pragma unroll
  for (int ni = 0; ni < 4; ++ni)
#pragma unroll
    for (int i = 0; i < 4; ++i) {
      const int n = ni * 16 + quad * 4 + i;
#pragma unroll
      for (int mi = 0; mi < 4; ++mi) s[ni][mi][i] += bh[n * 64 + mi * 16 + l15];
    }
  float inv[4][4];
#pragma unroll
  for (int ni = 0; ni < 4; ++ni)
#pragma unroll
    for (int i = 0; i < 4; ++i) {
      float mx = fmaxf(fmaxf(s[ni][0][i], s[ni][1][i]), fmaxf(s[ni][2][i], s[ni][3][i]));
      for (int off = 1; off < 16; off <<= 1) mx = fmaxf(mx, __shfl_xor(mx, off));
      float sum = 0.f;
#pragma unroll
      for (int mi = 0; mi < 4; ++mi) {
        float e = __expf(s[ni][mi][i] - mx);
        s[ni][mi][i] = e;
        sum += e;
      }
      for (int off = 1; off < 16; off <<= 1) sum += __shfl_xor(sum, off);
      inv[ni][i] = 1.0f / sum;
    }
#pragma unroll
  for (int ni = 0; ni < 4; ++ni)
#pragma unroll
    for (int i = 0; i < 4; ++i) {
      const int n = ni * 16 + quad * 4 + i;
#pragma unroll
      for (int mi = 0; mi < 4; ++mi)
        Psc[n * 72 + mi * 16 + l15] = (half_t)(s[ni][mi][i] * inv[ni][i]);
    }
  __builtin_amdgcn_s_waitcnt(0);  // P writes -> own reads

  // ---- PV ----
  half8 av[2][2];
#pragma unroll
  for (int ci = 0; ci < 2; ++ci)
#pragma unroll
    for (int k2 = 0; k2 < 2; ++k2)
      av[ci][k2] = *(const half8*)(vsc + (ci * 16 + l15) * 72 + k2 * 32 + quad * 8);
  float4v oa[2][4];
#pragma unroll
  for (int ci = 0; ci < 2; ++ci)
#pragma unroll
    for (int ni = 0; ni < 4; ++ni) {
      float4v z = {0.f, 0.f, 0.f, 0.f};
      oa[ci][ni] = z;
    }
#pragma unroll
  for (int ni = 0; ni < 4; ++ni)
#pragma unroll
    for (int k2 = 0; k2 < 2; ++k2) {
      half8 bp = *(const half8*)&Psc[(ni * 16 + l15) * 72 + k2 * 32 + quad * 8];
#pragma unroll
      for (int ci = 0; ci < 2; ++ci)
        oa[ci][ni] = __builtin_amdgcn_mfma_f32_16x16x32_f16(av[ci][k2], bp, oa[ci][ni], 0, 0, 0);
    }

  __syncthreads();  // all waves done reading xlp -> xa may overwrite it

  // ---- xa -> LDS [px][264] ----
#pragma unroll
  for (int ci = 0; ci < 2; ++ci)
#pragma unroll
    for (int ni = 0; ni < 4; ++ni) {
      half4v h = {(half_t)oa[ci][ni].x, (half_t)oa[ci][ni].y,
                  (half_t)oa[ci][ni].z, (half_t)oa[ci][ni].w};
      *(half4v*)(xa + (ni * 16 + l15) * 264 + head * 32 + ci * 16 + quad * 4) = h;
    }
  __syncthreads();

  // ---- proj: wave owns o-rows [32*wave, 32*wave+32) ----
  float4v pacc[2][4];
#pragma unroll
  for (int mi = 0; mi < 2; ++mi)
#pragma unroll
    for (int ni = 0; ni < 4; ++ni) {
      float4v z = {0.f, 0.f, 0.f, 0.f};
      pacc[mi][ni] = z;
    }
#pragma unroll
  for (int kh = 0; kh < 8; ++kh) {
    half8 af[2], bf[4];
#pragma unroll
    for (int mi = 0; mi < 2; ++mi)
      af[mi] = *(const half8*)(pw + (wave * 32 + mi * 16 + l15) * 256 + kh * 32 + quad * 8);
#pragma unroll
    for (int ni = 0; ni < 4; ++ni)
      bf[ni] = *(const half8*)&xa[(ni * 16 + l15) * 264 + kh * 32 + quad * 8];
#pragma unroll
    for (int mi = 0; mi < 2; ++mi)
#pragma unroll
      for (int ni = 0; ni < 4; ++ni)
        pacc[mi][ni] = __builtin_amdgcn_mfma_f32_16x16x32_f16(
            af[mi], bf[ni], pacc[mi][ni], 0, 0, 0);
  }
#pragma unroll
  for (int mi = 0; mi < 2; ++mi) {
    const float4v b4 = *(const float4v*)&projb[wave * 32 + mi * 16 + quad * 4];
#pragma unroll
    for (int ni = 0; ni < 4; ++ni) {
      pacc[mi][ni].x += b4.x;
      pacc[mi][ni].y += b4.y;
      pacc[mi][ni].z += b4.z;
      pacc[mi][ni].w += b4.w;
    }
  }

  // ---- transpose epilogue: 4 rounds of 64 o-rows via T[64][68] fp32 ----
  const int b = bd / 100, d = bd % 100;
  const size_t bdbase = (size_t)b * 1638400 + (size_t)d * 64;
  const int tr = tid >> 3;             // 0..63
  const int col0 = (tid & 7) * 8;
  for (int r = 0; r < 4; ++r) {
    __syncthreads();                   // r=0: also guards xa reads done
    if ((wave >> 1) == r) {
      const int rb = (wave & 1) * 32;
#pragma unroll
      for (int mi = 0; mi < 2; ++mi)
#pragma unroll
        for (int ni = 0; ni < 4; ++ni)
#pragma unroll
          for (int iv = 0; iv < 4; ++iv)
            T[(rb + mi * 16 + quad * 4 + iv) * 68 + ni * 16 + l15] = pacc[mi][ni][iv];
    }
    __syncthreads();
    const int o = r * 64 + tr;
    float* dst = out32 + bdbase + (size_t)o * 6400 + col0;
    const float* srcT = &T[tr * 68 + col0];
    *(float4v*)dst = *(const float4v*)srcT;
    *(float4v*)(dst + 4) = *(const float4v*)(srcT + 4);
  }
}

// ---------------- launch ----------------
extern "C" void kernel_launch(void* const* d_in, const int* in_sizes, int n_in,
                              void* d_out, int out_size, void* d_ws, size_t ws_size,
                              hipStream_t stream) {
  const float* x        = (const float*)d_in[0];
  const float* dwconv_w = (const float*)d_in[1];
  const float* dwconv_b = (const float*)d_in[2];
  const float* qkv_w    = (const float*)d_in[3];
  const float* qkv_b    = (const float*)d_in[4];
  const float* proj_w   = (const float*)d_in[5];
  const float* proj_b   = (const float*)d_in[6];
  const float* rpb      = (const float*)d_in[7];
  float* out = (float*)d_out;

  char* ws = (char*)d_ws;
  size_t off = 0;
  half_t* xpad = (half_t*)(ws + off); off += 40960000;   // 800*100*256 fp16
  half_t* xl   = (half_t*)(ws + off); off += 26214400;   // 51200*256 fp16
  half_t* Wt   = (half_t*)(ws + off); off += 1179648;    // [9][256][256]
  half_t* qw16 = (half_t*)(ws + off); off += 393216;
  half_t* pw16 = (half_t*)(ws + off); off += 131072;
  float*  btab = (float*)(ws + off);  off += 131072;     // [8][64][64]

  prep_all<<<1088, 256, 0, stream>>>(x, dwconv_w, qkv_w, proj_w, rpb,
                                     xpad, Wt, qw16, pw16, btab);
  conv_kernel<<<800, 256, 0, stream>>>(Wt, xpad, dwconv_b, xl);
  fused_tail3<<<800, 512, 0, stream>>>(xl, qw16, qkv_b, btab, pw16, proj_b, out);
}

// Round 7
// 296.359 us; speedup vs baseline: 1.1378x; 1.1378x over previous
//
#include <hip/hip_runtime.h>
#include <cstdint>
#include <cstddef>

// ---------------- problem constants ----------------
#define SCALEQ 0.17677669529663689f // 32^-0.5

typedef _Float16 half_t;
typedef _Float16 half8   __attribute__((ext_vector_type(8)));
typedef _Float16 half4v  __attribute__((ext_vector_type(4)));
typedef float    float4v __attribute__((ext_vector_type(4)));

#define GLDS16(gp, lp)                                                        \
  __builtin_amdgcn_global_load_lds(                                           \
      (const __attribute__((address_space(1))) void*)(gp),                    \
      (__attribute__((address_space(3))) void*)(lp), 16, 0, 0)

// ---------------- merged prep kernel (r5-verified) ----------------
__global__ __launch_bounds__(256) void prep_all(
    const float* __restrict__ x, const float* __restrict__ dwconv_w,
    const float* __restrict__ qkv_w, const float* __restrict__ proj_w,
    const float* __restrict__ rpb, half_t* __restrict__ xpad,
    half_t* __restrict__ Wt, half_t* __restrict__ qw16,
    half_t* __restrict__ pw16, float* __restrict__ btab) {
  __shared__ float tile[128 * 65];
  const int blk = blockIdx.x, t = threadIdx.x;
  if (blk < 800) {
    const int bd = blk, b = bd / 100, d = bd % 100;
    for (int hf = 0; hf < 2; ++hf) {
      for (int i = 0; i < 32; ++i) {
        int idx = i * 256 + t, c = idx >> 6, hw = idx & 63;
        tile[c * 65 + hw] = x[(size_t)((b * 256 + hf * 128 + c) * 100 + d) * 64 + hw];
      }
      __syncthreads();
      for (int i = 0; i < 50; ++i) {
        int idx = i * 256 + t, cell = idx >> 7, c = idx & 127;
        int hh = cell / 10, ww = cell % 10;
        float v = 0.f;
        if (hh >= 1 && hh <= 8 && ww >= 1 && ww <= 8)
          v = tile[c * 65 + (hh - 1) * 8 + (ww - 1)];
        xpad[(size_t)(bd * 100 + cell) * 256 + hf * 128 + c] = (half_t)v;
      }
      __syncthreads();
    }
  } else if (blk < 944) {        // convw: Wt[tap][o][c]
    const int base = (blk - 800) * 4096;
#pragma unroll
    for (int i = 0; i < 16; ++i) {
      int idx = base + i * 256 + t;
      int tap = idx >> 16, rem = idx & 65535;
      int o = rem >> 8, c = rem & 255;
      Wt[idx] = (half_t)dwconv_w[(o * 256 + c) * 9 + tap];
    }
  } else if (blk < 1040) {       // qkvw (q rows pre-scaled)
    const int base = (blk - 944) * 2048;
#pragma unroll
    for (int i = 0; i < 8; ++i) {
      int idx = base + i * 256 + t;
      float v = qkv_w[idx];
      if (idx < 65536) v *= SCALEQ;
      qw16[idx] = (half_t)v;
    }
  } else if (blk < 1072) {       // projw
    const int base = (blk - 1040) * 2048;
#pragma unroll
    for (int i = 0; i < 8; ++i) {
      int idx = base + i * 256 + t;
      pw16[idx] = (half_t)proj_w[idx];
    }
  } else {                       // bias table btab[head][n][m]
    const int base = (blk - 1072) * 2048;
#pragma unroll
    for (int i = 0; i < 8; ++i) {
      int idx = base + i * 256 + t;
      int hd = idx >> 12, n = (idx >> 6) & 63, m = idx & 63;
      int h1 = n >> 3, w1 = n & 7, h2 = m >> 3, w2 = m & 7;
      int ridx = (h1 - h2 + 7) * 15 + (w1 - w2 + 7);
      btab[idx] = rpb[ridx * 8 + hd];
    }
  }
}

// ---------------- conv implicit GEMM (unchanged, verified) ----------------
__global__ __launch_bounds__(256) void conv_kernel(
    const half_t* __restrict__ Wt, const half_t* __restrict__ xpad,
    const float* __restrict__ convb, half_t* __restrict__ xl) {
  __shared__ __align__(16) half_t Asm[128 * 64];
  __shared__ __align__(16) half_t Bsm[128 * 64];
  const int blk = blockIdx.x;
  const int o0 = (blk & 1) * 128;
  const int n0 = (blk >> 1) * 128;
  const int tid = threadIdx.x;
  const int wave = tid >> 6, lane = tid & 63;
  const int l15 = lane & 15, quad = lane >> 4;
  const int wm = wave >> 1, wn = wave & 1;
  const int srow = tid >> 3;
  const int cg = (tid & 7) ^ (srow & 7);

  int pixbase[4], arow[4];
#pragma unroll
  for (int i = 0; i < 4; ++i) {
    int P = n0 + srow + i * 32;
    int bd = P >> 6, hw = P & 63;
    pixbase[i] = (bd * 100 + (hw >> 3) * 10 + (hw & 7)) * 512 + cg * 16;
    arow[i] = (o0 + srow + i * 32) * 512 + cg * 16;
  }

  float4v acc[4][4];
#pragma unroll
  for (int mi = 0; mi < 4; ++mi)
#pragma unroll
    for (int ni = 0; ni < 4; ++ni) {
      float4v z = {0.f, 0.f, 0.f, 0.f};
      acc[mi][ni] = z;
    }

  const char* xpc = (const char*)xpad;
  for (int tap = 0; tap < 9; ++tap) {
    const char* wt = (const char*)Wt + tap * 131072;
    const int toff = ((tap / 3) * 10 + (tap % 3)) * 512;
    for (int c0 = 0; c0 < 512; c0 += 128) {
#pragma unroll
      for (int i = 0; i < 4; ++i) {
        GLDS16(wt + arow[i] + c0, (char*)Asm + i * 4096 + wave * 1024);
        GLDS16(xpc + pixbase[i] + toff + c0, (char*)Bsm + i * 4096 + wave * 1024);
      }
      __syncthreads();
#pragma unroll
      for (int kh = 0; kh < 2; ++kh) {
        half8 af[4], bf[4];
#pragma unroll
        for (int mi = 0; mi < 4; ++mi) {
          int r = wm * 64 + mi * 16 + l15;
          af[mi] = *(const half8*)&Asm[r * 64 + (((kh * 4 + quad) ^ (r & 7)) * 8)];
        }
#pragma unroll
        for (int ni = 0; ni < 4; ++ni) {
          int r = wn * 64 + ni * 16 + l15;
          bf[ni] = *(const half8*)&Bsm[r * 64 + (((kh * 4 + quad) ^ (r & 7)) * 8)];
        }
#pragma unroll
        for (int mi = 0; mi < 4; ++mi)
#pragma unroll
          for (int ni = 0; ni < 4; ++ni)
            acc[mi][ni] = __builtin_amdgcn_mfma_f32_16x16x32_f16(
                af[mi], bf[ni], acc[mi][ni], 0, 0, 0);
      }
      __syncthreads();
    }
  }
#pragma unroll
  for (int mi = 0; mi < 4; ++mi) {
    const int o4 = o0 + wm * 64 + mi * 16 + quad * 4;
    const float b0 = convb[o4], b1 = convb[o4 + 1], b2 = convb[o4 + 2], b3 = convb[o4 + 3];
#pragma unroll
    for (int ni = 0; ni < 4; ++ni) {
      const int P = n0 + wn * 64 + ni * 16 + l15;
      half4v h;
      h.x = (half_t)(acc[mi][ni].x + b0);
      h.y = (half_t)(acc[mi][ni].y + b1);
      h.z = (half_t)(acc[mi][ni].z + b2);
      h.w = (half_t)(acc[mi][ni].w + b3);
      *(half4v*)(xl + (size_t)P * 256 + o4) = h;
    }
  }
}

// ---------------- fused qkv + attention + proj (r5 structure + prefetch) ----
// grid 800, block 512 (8 waves = 1 wave per head). r7: register prefetch of
// weights across phase boundaries (q before stage barrier; k during q-loop;
// v during k-loop; proj during PV; bias before QK MFMAs). Layouts identical
// to r5-verified fused_tail2.
__global__ __launch_bounds__(512) void fused_tail4(
    const half_t* __restrict__ xlg, const half_t* __restrict__ qw,
    const float* __restrict__ qkvb, const float* __restrict__ btab,
    const half_t* __restrict__ pw, const float* __restrict__ projb,
    float* __restrict__ out32) {
  __shared__ __align__(16) half_t LS[78336];   // 156672 B
  const int bd = blockIdx.x;
  const int tid = threadIdx.x;
  const int wave = tid >> 6, lane = tid & 63;
  const int l15 = lane & 15, quad = lane >> 4;
  const int head = wave;

  half_t* xlp = LS;
  half_t* xa = LS;                      // [64][264] overlay after barrier
  float* T = (float*)LS;                // [64][68] fp32 overlay at the end
  half_t* scr = LS + 16896 + wave * 7680;
  half_t* qsc = scr;                    // [64][40]
  half_t* ksc = scr + 2560;             // [64][40]
  half_t* vsc = scr + 5120;             // [32][72]
  half_t* Psc = scr;                    // [64][72] (over q+k)

  const half_t* Wq0 = qw + head * 32 * 256;
  const half_t* Wk0 = qw + 65536 + head * 32 * 256;
  const half_t* Wv0 = qw + 131072 + head * 32 * 256;

  // ---- preload q-part weights (independent of staging) ----
  half8 wq[8][2];
#pragma unroll
  for (int kh = 0; kh < 8; ++kh)
#pragma unroll
    for (int mi = 0; mi < 2; ++mi)
      wq[kh][mi] = *(const half8*)(Wq0 + (mi * 16 + l15) * 256 + kh * 32 + quad * 8);

  // ---- stage xl[bd] (32 KB), XOR-swizzled 16B chunks ----
  {
    const char* src = (const char*)(xlg + (size_t)bd * 64 * 256);
#pragma unroll
    for (int i = 0; i < 4; ++i) {
      int row = i * 16 + wave * 2 + (lane >> 5);
      int sch = (lane & 31) ^ (row & 7);
      GLDS16(src + row * 512 + sch * 16, (char*)xlp + (i * 16 + wave * 2) * 512);
    }
  }
  __syncthreads();

  // ---- q GEMM (uses wq), prefetch k weights ----
  half8 wk[8][2];
  {
    float4v acc[2][4];
#pragma unroll
    for (int mi = 0; mi < 2; ++mi)
#pragma unroll
      for (int ni = 0; ni < 4; ++ni) {
        float4v z = {0.f, 0.f, 0.f, 0.f};
        acc[mi][ni] = z;
      }
#pragma unroll
    for (int kh = 0; kh < 8; ++kh) {
      half8 bf[4];
#pragma unroll
      for (int ni = 0; ni < 4; ++ni) {
        int r = ni * 16 + l15;
        bf[ni] = *(const half8*)&xlp[r * 256 + (((kh * 4 + quad) ^ (r & 7)) * 8)];
      }
#pragma unroll
      for (int mi = 0; mi < 2; ++mi)
        wk[kh][mi] = *(const half8*)(Wk0 + (mi * 16 + l15) * 256 + kh * 32 + quad * 8);
#pragma unroll
      for (int mi = 0; mi < 2; ++mi)
#pragma unroll
        for (int ni = 0; ni < 4; ++ni)
          acc[mi][ni] = __builtin_amdgcn_mfma_f32_16x16x32_f16(
              wq[kh][mi], bf[ni], acc[mi][ni], 0, 0, 0);
    }
#pragma unroll
    for (int mi = 0; mi < 2; ++mi) {
      const float4v b4 = *(const float4v*)&qkvb[head * 32 + mi * 16 + quad * 4];
#pragma unroll
      for (int ni = 0; ni < 4; ++ni) {
        half4v h;
        h.x = (half_t)(acc[mi][ni].x + b4.x * SCALEQ);
        h.y = (half_t)(acc[mi][ni].y + b4.y * SCALEQ);
        h.z = (half_t)(acc[mi][ni].z + b4.z * SCALEQ);
        h.w = (half_t)(acc[mi][ni].w + b4.w * SCALEQ);
        *(half4v*)(qsc + (ni * 16 + l15) * 40 + mi * 16 + quad * 4) = h;
      }
    }
  }

  // ---- k GEMM (uses wk), prefetch v weights ----
  half8 wv[8][2];
  {
    float4v acc[2][4];
#pragma unroll
    for (int mi = 0; mi < 2; ++mi)
#pragma unroll
      for (int ni = 0; ni < 4; ++ni) {
        float4v z = {0.f, 0.f, 0.f, 0.f};
        acc[mi][ni] = z;
      }
#pragma unroll
    for (int kh = 0; kh < 8; ++kh) {
      half8 bf[4];
#pragma unroll
      for (int ni = 0; ni < 4; ++ni) {
        int r = ni * 16 + l15;
        bf[ni] = *(const half8*)&xlp[r * 256 + (((kh * 4 + quad) ^ (r & 7)) * 8)];
      }
#pragma unroll
      for (int mi = 0; mi < 2; ++mi)
        wv[kh][mi] = *(const half8*)(Wv0 + (mi * 16 + l15) * 256 + kh * 32 + quad * 8);
#pragma unroll
      for (int mi = 0; mi < 2; ++mi)
#pragma unroll
        for (int ni = 0; ni < 4; ++ni)
          acc[mi][ni] = __builtin_amdgcn_mfma_f32_16x16x32_f16(
              wk[kh][mi], bf[ni], acc[mi][ni], 0, 0, 0);
    }
#pragma unroll
    for (int mi = 0; mi < 2; ++mi) {
      const float4v b4 = *(const float4v*)&qkvb[256 + head * 32 + mi * 16 + quad * 4];
#pragma unroll
      for (int ni = 0; ni < 4; ++ni) {
        half4v h;
        h.x = (half_t)(acc[mi][ni].x + b4.x);
        h.y = (half_t)(acc[mi][ni].y + b4.y);
        h.z = (half_t)(acc[mi][ni].z + b4.z);
        h.w = (half_t)(acc[mi][ni].w + b4.w);
        *(half4v*)(ksc + (ni * 16 + l15) * 40 + mi * 16 + quad * 4) = h;
      }
    }
  }

  // ---- v GEMM (uses wv) -> vsc [32][72] transposed scalar writes ----
  {
    float4v acc[2][4];
#pragma unroll
    for (int mi = 0; mi < 2; ++mi)
#pragma unroll
      for (int ni = 0; ni < 4; ++ni) {
        float4v z = {0.f, 0.f, 0.f, 0.f};
        acc[mi][ni] = z;
      }
#pragma unroll
    for (int kh = 0; kh < 8; ++kh) {
      half8 bf[4];
#pragma unroll
      for (int ni = 0; ni < 4; ++ni) {
        int r = ni * 16 + l15;
        bf[ni] = *(const half8*)&xlp[r * 256 + (((kh * 4 + quad) ^ (r & 7)) * 8)];
      }
#pragma unroll
      for (int mi = 0; mi < 2; ++mi)
#pragma unroll
        for (int ni = 0; ni < 4; ++ni)
          acc[mi][ni] = __builtin_amdgcn_mfma_f32_16x16x32_f16(
              wv[kh][mi], bf[ni], acc[mi][ni], 0, 0, 0);
    }
#pragma unroll
    for (int mi = 0; mi < 2; ++mi) {
      const float4v b4 = *(const float4v*)&qkvb[512 + head * 32 + mi * 16 + quad * 4];
#pragma unroll
      for (int ni = 0; ni < 4; ++ni) {
#pragma unroll
        for (int iv = 0; iv < 4; ++iv)
          vsc[(mi * 16 + quad * 4 + iv) * 72 + ni * 16 + l15] =
              (half_t)(acc[mi][ni][iv] + b4[iv]);
      }
    }
  }

  __builtin_amdgcn_s_waitcnt(0);  // q/k/v scratch writes -> own reads

  // ---- QK^T + bias + softmax ----
  half8 aq[4], bk[4];
#pragma unroll
  for (int i = 0; i < 4; ++i) {
    aq[i] = *(const half8*)(qsc + (i * 16 + l15) * 40 + quad * 8);
    bk[i] = *(const half8*)(ksc + (i * 16 + l15) * 40 + quad * 8);
  }
  // prefetch bias table into registers (L2-hot; hidden under QK MFMAs)
  const float* bh = btab + head * 4096;
  float br[4][4][4];
#pragma unroll
  for (int ni = 0; ni < 4; ++ni)
#pragma unroll
    for (int i = 0; i < 4; ++i) {
      const int n = ni * 16 + quad * 4 + i;
#pragma unroll
      for (int mi = 0; mi < 4; ++mi)
        br[ni][i][mi] = bh[n * 64 + mi * 16 + l15];
    }
  float4v s[4][4];
#pragma unroll
  for (int ni = 0; ni < 4; ++ni)
#pragma unroll
    for (int mi = 0; mi < 4; ++mi) {
      float4v z = {0.f, 0.f, 0.f, 0.f};
      s[ni][mi] = __builtin_amdgcn_mfma_f32_16x16x32_f16(aq[ni], bk[mi], z, 0, 0, 0);
    }
#pragma unroll
  for (int ni = 0; ni < 4; ++ni)
#pragma unroll
    for (int i = 0; i < 4; ++i)
#pragma unroll
      for (int mi = 0; mi < 4; ++mi) s[ni][mi][i] += br[ni][i][mi];
  float inv[4][4];
#pragma unroll
  for (int ni = 0; ni < 4; ++ni)
#pragma unroll
    for (int i = 0; i < 4; ++i) {
      float mx = fmaxf(fmaxf(s[ni][0][i], s[ni][1][i]), fmaxf(s[ni][2][i], s[ni][3][i]));
      for (int off = 1; off < 16; off <<= 1) mx = fmaxf(mx, __shfl_xor(mx, off));
      float sum = 0.f;
#pragma unroll
      for (int mi = 0; mi < 4; ++mi) {
        float e = __expf(s[ni][mi][i] - mx);
        s[ni][mi][i] = e;
        sum += e;
      }
      for (int off = 1; off < 16; off <<= 1) sum += __shfl_xor(sum, off);
      inv[ni][i] = 1.0f / sum;
    }
#pragma unroll
  for (int ni = 0; ni < 4; ++ni)
#pragma unroll
    for (int i = 0; i < 4; ++i) {
      const int n = ni * 16 + quad * 4 + i;
#pragma unroll
      for (int mi = 0; mi < 4; ++mi)
        Psc[n * 72 + mi * 16 + l15] = (half_t)(s[ni][mi][i] * inv[ni][i]);
    }
  __builtin_amdgcn_s_waitcnt(0);  // P writes -> own reads

  // ---- PV + proj-weight prefetch ----
  half8 wp[8][2];
#pragma unroll
  for (int kh = 0; kh < 8; ++kh)
#pragma unroll
    for (int mi = 0; mi < 2; ++mi)
      wp[kh][mi] = *(const half8*)(pw + (wave * 32 + mi * 16 + l15) * 256 + kh * 32 + quad * 8);
  half8 av[2][2];
#pragma unroll
  for (int ci = 0; ci < 2; ++ci)
#pragma unroll
    for (int k2 = 0; k2 < 2; ++k2)
      av[ci][k2] = *(const half8*)(vsc + (ci * 16 + l15) * 72 + k2 * 32 + quad * 8);
  float4v oa[2][4];
#pragma unroll
  for (int ci = 0; ci < 2; ++ci)
#pragma unroll
    for (int ni = 0; ni < 4; ++ni) {
      float4v z = {0.f, 0.f, 0.f, 0.f};
      oa[ci][ni] = z;
    }
#pragma unroll
  for (int ni = 0; ni < 4; ++ni)
#pragma unroll
    for (int k2 = 0; k2 < 2; ++k2) {
      half8 bp = *(const half8*)&Psc[(ni * 16 + l15) * 72 + k2 * 32 + quad * 8];
#pragma unroll
      for (int ci = 0; ci < 2; ++ci)
        oa[ci][ni] = __builtin_amdgcn_mfma_f32_16x16x32_f16(av[ci][k2], bp, oa[ci][ni], 0, 0, 0);
    }

  __syncthreads();  // all waves done reading xlp -> xa may overwrite it

  // ---- xa -> LDS [px][264] ----
#pragma unroll
  for (int ci = 0; ci < 2; ++ci)
#pragma unroll
    for (int ni = 0; ni < 4; ++ni) {
      half4v h = {(half_t)oa[ci][ni].x, (half_t)oa[ci][ni].y,
                  (half_t)oa[ci][ni].z, (half_t)oa[ci][ni].w};
      *(half4v*)(xa + (ni * 16 + l15) * 264 + head * 32 + ci * 16 + quad * 4) = h;
    }
  __syncthreads();

  // ---- proj: wave owns o-rows [32*wave, +32), weights from registers ----
  float4v pacc[2][4];
#pragma unroll
  for (int mi = 0; mi < 2; ++mi)
#pragma unroll
    for (int ni = 0; ni < 4; ++ni) {
      float4v z = {0.f, 0.f, 0.f, 0.f};
      pacc[mi][ni] = z;
    }
#pragma unroll
  for (int kh = 0; kh < 8; ++kh) {
    half8 bf[4];
#pragma unroll
    for (int ni = 0; ni < 4; ++ni)
      bf[ni] = *(const half8*)&xa[(ni * 16 + l15) * 264 + kh * 32 + quad * 8];
#pragma unroll
    for (int mi = 0; mi < 2; ++mi)
#pragma unroll
      for (int ni = 0; ni < 4; ++ni)
        pacc[mi][ni] = __builtin_amdgcn_mfma_f32_16x16x32_f16(
            wp[kh][mi], bf[ni], pacc[mi][ni], 0, 0, 0);
  }
#pragma unroll
  for (int mi = 0; mi < 2; ++mi) {
    const float4v b4 = *(const float4v*)&projb[wave * 32 + mi * 16 + quad * 4];
#pragma unroll
    for (int ni = 0; ni < 4; ++ni) {
      pacc[mi][ni].x += b4.x;
      pacc[mi][ni].y += b4.y;
      pacc[mi][ni].z += b4.z;
      pacc[mi][ni].w += b4.w;
    }
  }

  // ---- transpose epilogue: 4 rounds of 64 o-rows via T[64][68] fp32 ----
  const int b = bd / 100, d = bd % 100;
  const size_t bdbase = (size_t)b * 1638400 + (size_t)d * 64;
  const int tr = tid >> 3;             // 0..63
  const int col0 = (tid & 7) * 8;
  for (int r = 0; r < 4; ++r) {
    __syncthreads();                   // r=0: also guards xa reads done
    if ((wave >> 1) == r) {
      const int rb = (wave & 1) * 32;
#pragma unroll
      for (int mi = 0; mi < 2; ++mi)
#pragma unroll
        for (int ni = 0; ni < 4; ++ni)
#pragma unroll
          for (int iv = 0; iv < 4; ++iv)
            T[(rb + mi * 16 + quad * 4 + iv) * 68 + ni * 16 + l15] = pacc[mi][ni][iv];
    }
    __syncthreads();
    const int o = r * 64 + tr;
    float* dst = out32 + bdbase + (size_t)o * 6400 + col0;
    const float* srcT = &T[tr * 68 + col0];
    *(float4v*)dst = *(const float4v*)srcT;
    *(float4v*)(dst + 4) = *(const float4v*)(srcT + 4);
  }
}

// ---------------- launch ----------------
extern "C" void kernel_launch(void* const* d_in, const int* in_sizes, int n_in,
                              void* d_out, int out_size, void* d_ws, size_t ws_size,
                              hipStream_t stream) {
  const float* x        = (const float*)d_in[0];
  const float* dwconv_w = (const float*)d_in[1];
  const float* dwconv_b = (const float*)d_in[2];
  const float* qkv_w    = (const float*)d_in[3];
  const float* qkv_b    = (const float*)d_in[4];
  const float* proj_w   = (const float*)d_in[5];
  const float* proj_b   = (const float*)d_in[6];
  const float* rpb      = (const float*)d_in[7];
  float* out = (float*)d_out;

  char* ws = (char*)d_ws;
  size_t off = 0;
  half_t* xpad = (half_t*)(ws + off); off += 40960000;   // 800*100*256 fp16
  half_t* xl   = (half_t*)(ws + off); off += 26214400;   // 51200*256 fp16
  half_t* Wt   = (half_t*)(ws + off); off += 1179648;    // [9][256][256]
  half_t* qw16 = (half_t*)(ws + off); off += 393216;
  half_t* pw16 = (half_t*)(ws + off); off += 131072;
  float*  btab = (float*)(ws + off);  off += 131072;     // [8][64][64]

  prep_all<<<1088, 256, 0, stream>>>(x, dwconv_w, qkv_w, proj_w, rpb,
                                     xpad, Wt, qw16, pw16, btab);
  conv_kernel<<<800, 256, 0, stream>>>(Wt, xpad, dwconv_b, xl);
  fused_tail4<<<800, 512, 0, stream>>>(xl, qw16, qkv_b, btab, pw16, proj_b, out);
}